// Round 7
// baseline (313.872 us; speedup 1.0000x reference)
//
#include <hip/hip_runtime.h>

// B=8, N=1024, C=1024, H=16, HD=64
// R7: GEMMs = 4-stage LDS pipeline (64KB), prefetch distance 3, vmcnt(8)
//     barriers, XCD-aware 1D block swizzle (B-tiles pinned per-XCD L2).
//     Attention/converts unchanged from R6.

typedef __attribute__((ext_vector_type(8))) short bf16x8;
typedef __attribute__((ext_vector_type(4))) float f32x4;

__device__ __forceinline__ short f2bf(float f) {
    union { float f; unsigned u; } x;
    x.f = f;
    unsigned r = x.u + 0x7fffu + ((x.u >> 16) & 1u);  // RNE
    return (short)(r >> 16);
}

__device__ __forceinline__ void load_lds16(const void* g, void* l) {
    __builtin_amdgcn_global_load_lds((const __attribute__((address_space(1))) unsigned*)g,
                                     (__attribute__((address_space(3))) unsigned*)l,
                                     16, 0, 0);
}

// ---------------- merged fp32 -> bf16 convert ----------------
__global__ __launch_bounds__(256) void convert_all(const float* __restrict__ x,
                                                   const float* __restrict__ wqkv,
                                                   const float* __restrict__ wproj,
                                                   short* __restrict__ xb,
                                                   short* __restrict__ wqkvb,
                                                   short* __restrict__ wprojb) {
    int i = blockIdx.x * 256 + threadIdx.x;
    const float* src;
    short* dst;
    int j;
    if (i < 2097152)      { src = x;     dst = xb;     j = i; }
    else if (i < 2883584) { src = wqkv;  dst = wqkvb;  j = i - 2097152; }
    else                  { src = wproj; dst = wprojb; j = i - 2883584; }
    float4 v = *(const float4*)(src + j * 4);
    unsigned lo = (unsigned short)f2bf(v.x) | ((unsigned)(unsigned short)f2bf(v.y) << 16);
    unsigned hi = (unsigned short)f2bf(v.z) | ((unsigned)(unsigned short)f2bf(v.w) << 16);
    uint2 p; p.x = lo; p.y = hi;
    *(uint2*)(dst + j * 4) = p;
}

// ---------------- QKV GEMM: 4-stage pipeline, distance 3, XCD swizzle ----------------
// M=8192, N=3072, K=1024. 1536 blocks (1D). xcd=id&7 owns n-tiles {3x,3x+1,3x+2}.
__global__ __launch_bounds__(256) void gemm_qkv(const short* __restrict__ A,
                                                const short* __restrict__ Bt,
                                                short* __restrict__ q,
                                                short* __restrict__ k,
                                                short* __restrict__ vt) {
    __shared__ alignas(16) short As[4][128][32];   // 4-stage: 64 KB total
    __shared__ alignas(16) short Bs[4][128][32];
    const int K = 1024;
    const int id = blockIdx.x;
    const int xcd = id & 7, j = id >> 3;           // j: 0..191
    const int n0 = (xcd * 3 + (j >> 6)) * 128;     // 3 B-col-tiles pinned per XCD
    const int m0 = (j & 63) * 128;                 // A streams
    const int t = threadIdx.x;
    const int w = t >> 6, lane = t & 63, quad = lane >> 4, l16 = lane & 15;
    const int wm = (w >> 1) * 64, wn = (w & 1) * 64;
    const int srow = lane >> 2;
    const int sc8 = (lane & 3) * 8;

    const short* Abase = &A[(m0 + w * 32 + srow) * K + sc8];
    const short* Bbase = &Bt[(n0 + w * 32 + srow) * K + sc8];

    f32x4 acc[4][4];
    for (int mi = 0; mi < 4; ++mi)
        for (int ni = 0; ni < 4; ++ni)
            acc[mi][ni] = (f32x4){0.f, 0.f, 0.f, 0.f};

    // prologue: stage tiles 0,1,2 (12 outstanding loads)
    #pragma unroll
    for (int p = 0; p < 3; ++p) {
        load_lds16(Abase + p * 32,          &As[p][w * 32][0]);
        load_lds16(Abase + 16 * K + p * 32, &As[p][w * 32 + 16][0]);
        load_lds16(Bbase + p * 32,          &Bs[p][w * 32][0]);
        load_lds16(Bbase + 16 * K + p * 32, &Bs[p][w * 32 + 16][0]);
    }

    #pragma unroll
    for (int it = 0; it < 32; ++it) {
        if (it <= 29)      asm volatile("s_waitcnt vmcnt(8) lgkmcnt(0)" ::: "memory");
        else if (it == 30) asm volatile("s_waitcnt vmcnt(4) lgkmcnt(0)" ::: "memory");
        else               asm volatile("s_waitcnt vmcnt(0) lgkmcnt(0)" ::: "memory");
        asm volatile("s_barrier" ::: "memory");
        if (it < 29) {
            const int b3 = (it + 3) & 3;
            load_lds16(Abase + (it + 3) * 32,          &As[b3][w * 32][0]);
            load_lds16(Abase + 16 * K + (it + 3) * 32, &As[b3][w * 32 + 16][0]);
            load_lds16(Bbase + (it + 3) * 32,          &Bs[b3][w * 32][0]);
            load_lds16(Bbase + 16 * K + (it + 3) * 32, &Bs[b3][w * 32 + 16][0]);
        }
        const int cb = it & 3;
        bf16x8 af[4], bfr[4];
        for (int i = 0; i < 4; ++i) af[i]  = *(const bf16x8*)&As[cb][wm + i * 16 + l16][quad * 8];
        for (int i = 0; i < 4; ++i) bfr[i] = *(const bf16x8*)&Bs[cb][wn + i * 16 + l16][quad * 8];
        for (int mi = 0; mi < 4; ++mi)
            for (int ni = 0; ni < 4; ++ni)
                acc[mi][ni] = __builtin_amdgcn_mfma_f32_16x16x32_bf16(af[mi], bfr[ni], acc[mi][ni], 0, 0, 0);
    }

    const float QS = 0.125f * 1.44269504088896f;
    for (int ni = 0; ni < 4; ++ni) {
        int col = n0 + wn + ni * 16 + l16;
        int sect = col >> 10;
        int c = col & 1023;
        int h = c >> 6, d = c & 63;
        for (int mi = 0; mi < 4; ++mi) {
            for (int r = 0; r < 4; ++r) {
                int m = m0 + wm + mi * 16 + quad * 4 + r;
                int b = m >> 10, i = m & 1023;
                float v = acc[mi][ni][r];
                if (sect == 0)      q[((b * 16 + h) * 1024 + i) * 64 + d] = f2bf(v * QS);
                else if (sect == 1) k[((b * 16 + h) * 1024 + i) * 64 + d] = f2bf(v);
                else                vt[((b * 16 + h) * 64 + d) * 1024 + i] = f2bf(v);
            }
        }
    }
}

// ---------------- Flash attention (unchanged from R6) ----------------
__global__ __launch_bounds__(256) void attn_kernel(const short* __restrict__ q,
                                                   const short* __restrict__ k,
                                                   const short* __restrict__ vt,
                                                   short* __restrict__ ao) {
    __shared__ alignas(16) short Ks[64][72];
    __shared__ alignas(16) short Vs[64][72];
    __shared__ alignas(16) short Ps[4][32][72];

    const int bh = blockIdx.y, qt = blockIdx.x;
    const int t = threadIdx.x, w = t >> 6, lane = t & 63, quad = lane >> 4, l16 = lane & 15;
    const short* qg = q  + (bh * 1024 + qt * 128) * 64;
    const short* kg = k  + bh * 65536;
    const short* vg = vt + bh * 65536;

    bf16x8 qf[2][2];
    for (int mi = 0; mi < 2; ++mi) {
        const short* qr = qg + (w * 32 + mi * 16 + l16) * 64;
        qf[mi][0] = *(const bf16x8*)(qr + quad * 8);
        qf[mi][1] = *(const bf16x8*)(qr + 32 + quad * 8);
    }

    const int r0 = t >> 3,          c80 = (t & 7) * 8;
    const int r1 = (t + 256) >> 3,  c81 = c80;

    float rs[2][4];
    f32x4 oacc[2][4];
    for (int mi = 0; mi < 2; ++mi)
        for (int r = 0; r < 4; ++r) rs[mi][r] = 0.f;
    for (int mi = 0; mi < 2; ++mi)
        for (int nt = 0; nt < 4; ++nt) oacc[mi][nt] = (f32x4){0.f, 0.f, 0.f, 0.f};

    {
        float4 a = *(const float4*)&kg[r0 * 64 + c80];
        float4 b = *(const float4*)&kg[r1 * 64 + c81];
        float4 c = *(const float4*)&vg[r0 * 1024 + c80];
        float4 d = *(const float4*)&vg[r1 * 1024 + c81];
        *(float4*)&Ks[r0][c80] = a;  *(float4*)&Ks[r1][c81] = b;
        *(float4*)&Vs[r0][c80] = c;  *(float4*)&Vs[r1][c81] = d;
    }

    for (int jt = 0; jt < 16; ++jt) {
        asm volatile("s_waitcnt lgkmcnt(0)" ::: "memory");
        asm volatile("s_barrier" ::: "memory");

        float4 kr0, kr1, vr0, vr1;
        if (jt < 15) {
            int jn = jt + 1;
            kr0 = *(const float4*)&kg[(jn * 64 + r0) * 64 + c80];
            kr1 = *(const float4*)&kg[(jn * 64 + r1) * 64 + c81];
            vr0 = *(const float4*)&vg[r0 * 1024 + jn * 64 + c80];
            vr1 = *(const float4*)&vg[r1 * 1024 + jn * 64 + c81];
        }

        bf16x8 kf[4][2], vf[4][2];
        for (int nt = 0; nt < 4; ++nt) {
            kf[nt][0] = *(const bf16x8*)&Ks[nt * 16 + l16][quad * 8];
            kf[nt][1] = *(const bf16x8*)&Ks[nt * 16 + l16][32 + quad * 8];
            vf[nt][0] = *(const bf16x8*)&Vs[nt * 16 + l16][quad * 8];
            vf[nt][1] = *(const bf16x8*)&Vs[nt * 16 + l16][32 + quad * 8];
        }
        asm volatile("s_waitcnt lgkmcnt(0)" ::: "memory");
        asm volatile("s_barrier" ::: "memory");
        if (jt < 15) {
            *(float4*)&Ks[r0][c80] = kr0;  *(float4*)&Ks[r1][c81] = kr1;
            *(float4*)&Vs[r0][c80] = vr0;  *(float4*)&Vs[r1][c81] = vr1;
        }

        for (int mi = 0; mi < 2; ++mi) {
            f32x4 s[4];
            for (int nt = 0; nt < 4; ++nt) {
                f32x4 a = (f32x4){0.f, 0.f, 0.f, 0.f};
                a = __builtin_amdgcn_mfma_f32_16x16x32_bf16(qf[mi][0], kf[nt][0], a, 0, 0, 0);
                a = __builtin_amdgcn_mfma_f32_16x16x32_bf16(qf[mi][1], kf[nt][1], a, 0, 0, 0);
                s[nt] = a;
            }
            for (int nt = 0; nt < 4; ++nt) {
                for (int r = 0; r < 4; ++r) {
                    float p = __builtin_amdgcn_exp2f(s[nt][r]);
                    rs[mi][r] += p;
                    Ps[w][mi * 16 + quad * 4 + r][nt * 16 + l16] = f2bf(p);
                }
            }
            asm volatile("s_waitcnt lgkmcnt(0)" ::: "memory");
            bf16x8 pa0 = *(const bf16x8*)&Ps[w][mi * 16 + l16][quad * 8];
            bf16x8 pa1 = *(const bf16x8*)&Ps[w][mi * 16 + l16][32 + quad * 8];
            for (int nt = 0; nt < 4; ++nt) {
                oacc[mi][nt] = __builtin_amdgcn_mfma_f32_16x16x32_bf16(pa0, vf[nt][0], oacc[mi][nt], 0, 0, 0);
                oacc[mi][nt] = __builtin_amdgcn_mfma_f32_16x16x32_bf16(pa1, vf[nt][1], oacc[mi][nt], 0, 0, 0);
            }
        }
    }

    for (int mi = 0; mi < 2; ++mi)
        for (int r = 0; r < 4; ++r)
            for (int msk = 1; msk < 16; msk <<= 1)
                rs[mi][r] += __shfl_xor(rs[mi][r], msk, 64);

    const int b = bh >> 4, h = bh & 15;
    for (int mi = 0; mi < 2; ++mi) {
        for (int r = 0; r < 4; ++r) {
            float inv = 1.0f / rs[mi][r];
            int i = qt * 128 + w * 32 + mi * 16 + quad * 4 + r;
            for (int nt = 0; nt < 4; ++nt) {
                int d = nt * 16 + l16;
                ao[(b * 1024 + i) * 1024 + h * 64 + d] = f2bf(oacc[mi][nt][r] * inv);
            }
        }
    }
}

// ---------------- Out-proj GEMM: 4-stage pipeline, distance 3, XCD swizzle ----------------
// M=8192, N=1024. 512 blocks (1D). xcd=id&7 owns n-tile xcd (B-tile pinned in L2).
__global__ __launch_bounds__(256) void gemm_proj(const short* __restrict__ A,
                                                 const short* __restrict__ Bt,
                                                 const float* __restrict__ bias,
                                                 float* __restrict__ out) {
    __shared__ alignas(16) short As[4][128][32];
    __shared__ alignas(16) short Bs[4][128][32];
    const int K = 1024;
    const int id = blockIdx.x;
    const int n0 = (id & 7) * 128;
    const int m0 = (id >> 3) * 128;
    const int t = threadIdx.x;
    const int w = t >> 6, lane = t & 63, quad = lane >> 4, l16 = lane & 15;
    const int wm = (w >> 1) * 64, wn = (w & 1) * 64;
    const int srow = lane >> 2;
    const int sc8 = (lane & 3) * 8;

    const short* Abase = &A[(m0 + w * 32 + srow) * K + sc8];
    const short* Bbase = &Bt[(n0 + w * 32 + srow) * K + sc8];

    f32x4 acc[4][4];
    for (int mi = 0; mi < 4; ++mi)
        for (int ni = 0; ni < 4; ++ni)
            acc[mi][ni] = (f32x4){0.f, 0.f, 0.f, 0.f};

    #pragma unroll
    for (int p = 0; p < 3; ++p) {
        load_lds16(Abase + p * 32,          &As[p][w * 32][0]);
        load_lds16(Abase + 16 * K + p * 32, &As[p][w * 32 + 16][0]);
        load_lds16(Bbase + p * 32,          &Bs[p][w * 32][0]);
        load_lds16(Bbase + 16 * K + p * 32, &Bs[p][w * 32 + 16][0]);
    }

    #pragma unroll
    for (int it = 0; it < 32; ++it) {
        if (it <= 29)      asm volatile("s_waitcnt vmcnt(8) lgkmcnt(0)" ::: "memory");
        else if (it == 30) asm volatile("s_waitcnt vmcnt(4) lgkmcnt(0)" ::: "memory");
        else               asm volatile("s_waitcnt vmcnt(0) lgkmcnt(0)" ::: "memory");
        asm volatile("s_barrier" ::: "memory");
        if (it < 29) {
            const int b3 = (it + 3) & 3;
            load_lds16(Abase + (it + 3) * 32,          &As[b3][w * 32][0]);
            load_lds16(Abase + 16 * K + (it + 3) * 32, &As[b3][w * 32 + 16][0]);
            load_lds16(Bbase + (it + 3) * 32,          &Bs[b3][w * 32][0]);
            load_lds16(Bbase + 16 * K + (it + 3) * 32, &Bs[b3][w * 32 + 16][0]);
        }
        const int cb = it & 3;
        bf16x8 af[4], bfr[4];
        for (int i = 0; i < 4; ++i) af[i]  = *(const bf16x8*)&As[cb][wm + i * 16 + l16][quad * 8];
        for (int i = 0; i < 4; ++i) bfr[i] = *(const bf16x8*)&Bs[cb][wn + i * 16 + l16][quad * 8];
        for (int mi = 0; mi < 4; ++mi)
            for (int ni = 0; ni < 4; ++ni)
                acc[mi][ni] = __builtin_amdgcn_mfma_f32_16x16x32_bf16(af[mi], bfr[ni], acc[mi][ni], 0, 0, 0);
    }

    for (int ni = 0; ni < 4; ++ni) {
        int col = n0 + wn + ni * 16 + l16;
        float bv = bias[col];
        for (int mi = 0; mi < 4; ++mi) {
            for (int r = 0; r < 4; ++r) {
                int m = m0 + wm + mi * 16 + quad * 4 + r;
                out[m * 1024 + col] = acc[mi][ni][r] + bv;
            }
        }
    }
}

extern "C" void kernel_launch(void* const* d_in, const int* in_sizes, int n_in,
                              void* d_out, int out_size, void* d_ws, size_t ws_size,
                              hipStream_t stream) {
    const float* x      = (const float*)d_in[0];
    const float* w_qkv  = (const float*)d_in[1];
    const float* w_proj = (const float*)d_in[2];
    const float* b_proj = (const float*)d_in[3];
    float* out = (float*)d_out;

    char* ws = (char*)d_ws;
    short* xb     = (short*)(ws);
    short* wqkvb  = (short*)(ws + 16777216);
    short* wprojb = (short*)(ws + 23068672);
    short* qb     = (short*)(ws + 25165824);
    short* kb     = (short*)(ws + 41943040);
    short* vtb    = (short*)(ws + 58720256);
    short* aob    = (short*)(ws + 75497472);

    convert_all<<<12288, 256, 0, stream>>>(x, w_qkv, w_proj, xb, wqkvb, wprojb);
    gemm_qkv<<<1536, 256, 0, stream>>>(xb, wqkvb, qb, kb, vtb);
    attn_kernel<<<dim3(8, 128), 256, 0, stream>>>(qb, kb, vtb, aob);
    gemm_proj<<<512, 256, 0, stream>>>(aob, wprojb, b_proj, out);
}

// Round 8
// 266.966 us; speedup vs baseline: 1.1757x; 1.1757x over previous
//
#include <hip/hip_runtime.h>

// B=8, N=1024, C=1024, H=16, HD=64
// R8: GEMMs reverted to R6 (2D grid, 3-stage vmcnt(4) pipeline — the 2D
//     dispatch order gives A-tile L2/L3 reuse; R7's 1D swizzle tripled FETCH).
//     Attention rewritten: S^T = mfma(kf,qf) operand swap -> P stays in
//     registers as the B-operand fragment of 16x16x16 MFMA; PV as O^T=V^T P^T.
//     No Ps LDS, no mid-loop lgkm drains, 8B output stores.

typedef __attribute__((ext_vector_type(8))) short bf16x8;
typedef __attribute__((ext_vector_type(4))) short bf16x4;
typedef __attribute__((ext_vector_type(4))) float f32x4;

__device__ __forceinline__ short f2bf(float f) {
    union { float f; unsigned u; } x;
    x.f = f;
    unsigned r = x.u + 0x7fffu + ((x.u >> 16) & 1u);  // RNE
    return (short)(r >> 16);
}

__device__ __forceinline__ void load_lds16(const void* g, void* l) {
    __builtin_amdgcn_global_load_lds((const __attribute__((address_space(1))) unsigned*)g,
                                     (__attribute__((address_space(3))) unsigned*)l,
                                     16, 0, 0);
}

// ---------------- merged fp32 -> bf16 convert ----------------
__global__ __launch_bounds__(256) void convert_all(const float* __restrict__ x,
                                                   const float* __restrict__ wqkv,
                                                   const float* __restrict__ wproj,
                                                   short* __restrict__ xb,
                                                   short* __restrict__ wqkvb,
                                                   short* __restrict__ wprojb) {
    int i = blockIdx.x * 256 + threadIdx.x;
    const float* src;
    short* dst;
    int j;
    if (i < 2097152)      { src = x;     dst = xb;     j = i; }
    else if (i < 2883584) { src = wqkv;  dst = wqkvb;  j = i - 2097152; }
    else                  { src = wproj; dst = wprojb; j = i - 2883584; }
    float4 v = *(const float4*)(src + j * 4);
    unsigned lo = (unsigned short)f2bf(v.x) | ((unsigned)(unsigned short)f2bf(v.y) << 16);
    unsigned hi = (unsigned short)f2bf(v.z) | ((unsigned)(unsigned short)f2bf(v.w) << 16);
    uint2 p; p.x = lo; p.y = hi;
    *(uint2*)(dst + j * 4) = p;
}

// ---------------- QKV GEMM: 3-stage pipeline, vmcnt(4) barriers (R6) ----------------
__global__ __launch_bounds__(256) void gemm_qkv(const short* __restrict__ A,
                                                const short* __restrict__ Bt,
                                                short* __restrict__ q,
                                                short* __restrict__ k,
                                                short* __restrict__ vt) {
    __shared__ alignas(16) short As[3][128][32];
    __shared__ alignas(16) short Bs[3][128][32];
    const int K = 1024;
    const int m0 = blockIdx.y * 128;
    const int n0 = blockIdx.x * 128;
    const int t = threadIdx.x;
    const int w = t >> 6, lane = t & 63, quad = lane >> 4, l16 = lane & 15;
    const int wm = (w >> 1) * 64, wn = (w & 1) * 64;
    const int srow = lane >> 2;
    const int sc8 = (lane & 3) * 8;

    const short* Abase = &A[(m0 + w * 32 + srow) * K + sc8];
    const short* Bbase = &Bt[(n0 + w * 32 + srow) * K + sc8];

    f32x4 acc[4][4];
    for (int mi = 0; mi < 4; ++mi)
        for (int ni = 0; ni < 4; ++ni)
            acc[mi][ni] = (f32x4){0.f, 0.f, 0.f, 0.f};

    #pragma unroll
    for (int p = 0; p < 2; ++p) {
        load_lds16(Abase + p * 32,          &As[p][w * 32][0]);
        load_lds16(Abase + 16 * K + p * 32, &As[p][w * 32 + 16][0]);
        load_lds16(Bbase + p * 32,          &Bs[p][w * 32][0]);
        load_lds16(Bbase + 16 * K + p * 32, &Bs[p][w * 32 + 16][0]);
    }

    #pragma unroll
    for (int it = 0; it < 32; ++it) {
        if (it == 31) asm volatile("s_waitcnt vmcnt(0) lgkmcnt(0)" ::: "memory");
        else          asm volatile("s_waitcnt vmcnt(4) lgkmcnt(0)" ::: "memory");
        asm volatile("s_barrier" ::: "memory");
        if (it < 30) {
            const int b2 = (it + 2) % 3;
            load_lds16(Abase + (it + 2) * 32,          &As[b2][w * 32][0]);
            load_lds16(Abase + 16 * K + (it + 2) * 32, &As[b2][w * 32 + 16][0]);
            load_lds16(Bbase + (it + 2) * 32,          &Bs[b2][w * 32][0]);
            load_lds16(Bbase + 16 * K + (it + 2) * 32, &Bs[b2][w * 32 + 16][0]);
        }
        const int cb = it % 3;
        bf16x8 af[4], bfr[4];
        for (int i = 0; i < 4; ++i) af[i]  = *(const bf16x8*)&As[cb][wm + i * 16 + l16][quad * 8];
        for (int i = 0; i < 4; ++i) bfr[i] = *(const bf16x8*)&Bs[cb][wn + i * 16 + l16][quad * 8];
        for (int mi = 0; mi < 4; ++mi)
            for (int ni = 0; ni < 4; ++ni)
                acc[mi][ni] = __builtin_amdgcn_mfma_f32_16x16x32_bf16(af[mi], bfr[ni], acc[mi][ni], 0, 0, 0);
    }

    const float QS = 0.125f * 1.44269504088896f;
    for (int ni = 0; ni < 4; ++ni) {
        int col = n0 + wn + ni * 16 + l16;
        int sect = col >> 10;
        int c = col & 1023;
        int h = c >> 6, d = c & 63;
        for (int mi = 0; mi < 4; ++mi) {
            for (int r = 0; r < 4; ++r) {
                int m = m0 + wm + mi * 16 + quad * 4 + r;
                int b = m >> 10, i = m & 1023;
                float v = acc[mi][ni][r];
                if (sect == 0)      q[((b * 16 + h) * 1024 + i) * 64 + d] = f2bf(v * QS);
                else if (sect == 1) k[((b * 16 + h) * 1024 + i) * 64 + d] = f2bf(v);
                else                vt[((b * 16 + h) * 64 + d) * 1024 + i] = f2bf(v);
            }
        }
    }
}

// ---------------- Flash attention: register-resident P (S^T trick) ----------------
__global__ __launch_bounds__(256) void attn_kernel(const short* __restrict__ q,
                                                   const short* __restrict__ k,
                                                   const short* __restrict__ vt,
                                                   short* __restrict__ ao) {
    __shared__ alignas(16) short Ks[64][72];
    __shared__ alignas(16) short Vs[64][72];   // V^T tile [d][j]

    const int bh = blockIdx.y, qt = blockIdx.x;   // qt 0..7
    const int t = threadIdx.x, w = t >> 6, lane = t & 63, quad = lane >> 4, l16 = lane & 15;
    const short* qg = q  + (bh * 1024 + qt * 128) * 64;
    const short* kg = k  + bh * 65536;
    const short* vg = vt + bh * 65536;

    // Q fragments (dual-use A/B layout): Q[row=w*32+mi*16+l16][quad*8+j]
    bf16x8 qf[2][2];
    for (int mi = 0; mi < 2; ++mi) {
        const short* qr = qg + (w * 32 + mi * 16 + l16) * 64;
        qf[mi][0] = *(const bf16x8*)(qr + quad * 8);
        qf[mi][1] = *(const bf16x8*)(qr + 32 + quad * 8);
    }

    const int r0 = t >> 3,          c80 = (t & 7) * 8;
    const int r1 = (t + 256) >> 3,  c81 = c80;

    float rs[2] = {0.f, 0.f};      // per-lane partial row-sum for query m=l16 (quad's j slots)
    f32x4 oaccT[2][4];             // O^T: [mi][dt], row=d=dt*16+quad*4+r, col=m=l16
    for (int mi = 0; mi < 2; ++mi)
        for (int dt = 0; dt < 4; ++dt) oaccT[mi][dt] = (f32x4){0.f, 0.f, 0.f, 0.f};

    // stage tile 0
    {
        float4 a = *(const float4*)&kg[r0 * 64 + c80];
        float4 b = *(const float4*)&kg[r1 * 64 + c81];
        float4 c = *(const float4*)&vg[r0 * 1024 + c80];
        float4 d = *(const float4*)&vg[r1 * 1024 + c81];
        *(float4*)&Ks[r0][c80] = a;  *(float4*)&Ks[r1][c81] = b;
        *(float4*)&Vs[r0][c80] = c;  *(float4*)&Vs[r1][c81] = d;
    }

    for (int jt = 0; jt < 16; ++jt) {
        asm volatile("s_waitcnt lgkmcnt(0)" ::: "memory");  // staged writes done
        asm volatile("s_barrier" ::: "memory");             // A: tile visible

        // global prefetch of next tile (stays in flight across barrier B)
        float4 kr0, kr1, vr0, vr1;
        if (jt < 15) {
            int jn = jt + 1;
            kr0 = *(const float4*)&kg[(jn * 64 + r0) * 64 + c80];
            kr1 = *(const float4*)&kg[(jn * 64 + r1) * 64 + c81];
            vr0 = *(const float4*)&vg[r0 * 1024 + jn * 64 + c80];
            vr1 = *(const float4*)&vg[r1 * 1024 + jn * 64 + c81];
        }

        // hoist K fragments (A-op of S^T) and V^T fragments (A-op of PV^T)
        bf16x8 kf[4][2];
        bf16x4 vtf[4][4];   // [jsub][dt]: V^T[dt*16+l16][jsub*16+quad*4 .. +3]
        for (int js = 0; js < 4; ++js) {
            kf[js][0] = *(const bf16x8*)&Ks[js * 16 + l16][quad * 8];
            kf[js][1] = *(const bf16x8*)&Ks[js * 16 + l16][32 + quad * 8];
            for (int dt = 0; dt < 4; ++dt)
                vtf[js][dt] = *(const bf16x4*)&Vs[dt * 16 + l16][js * 16 + quad * 4];
        }
        asm volatile("s_waitcnt lgkmcnt(0)" ::: "memory");  // all LDS reads retired
        asm volatile("s_barrier" ::: "memory");             // B: safe to overwrite
        if (jt < 15) {
            *(float4*)&Ks[r0][c80] = kr0;  *(float4*)&Ks[r1][c81] = kr1;
            *(float4*)&Vs[r0][c80] = vr0;  *(float4*)&Vs[r1][c81] = vr1;
        }

        for (int mi = 0; mi < 2; ++mi) {
            for (int js = 0; js < 4; ++js) {
                // S^T tile: mfma(A=K, B=Q^T) -> lane holds S^T[quad*4+r][l16]
                f32x4 s = (f32x4){0.f, 0.f, 0.f, 0.f};
                s = __builtin_amdgcn_mfma_f32_16x16x32_bf16(kf[js][0], qf[mi][0], s, 0, 0, 0);
                s = __builtin_amdgcn_mfma_f32_16x16x32_bf16(kf[js][1], qf[mi][1], s, 0, 0, 0);
                // p = exp2(s) -> IS the 16x16x16 B-operand fragment (k=quad*4+r)
                bf16x4 pfrag;
                for (int r = 0; r < 4; ++r) {
                    float p = __builtin_amdgcn_exp2f(s[r]);
                    rs[mi] += p;
                    pfrag[r] = f2bf(p);
                }
                // O^T += V^T * P^T  (A=V^T frag, B=pfrag)
                for (int dt = 0; dt < 4; ++dt)
                    oaccT[mi][dt] = __builtin_amdgcn_mfma_f32_16x16x16bf16_1k(
                        vtf[js][dt], pfrag, oaccT[mi][dt], 0, 0, 0);
            }
        }
    }

    // row-sum: sum the 4 quad-partials for each m=l16
    for (int mi = 0; mi < 2; ++mi) {
        rs[mi] += __shfl_xor(rs[mi], 16, 64);
        rs[mi] += __shfl_xor(rs[mi], 32, 64);
    }

    const int b = bh >> 4, h = bh & 15;
    for (int mi = 0; mi < 2; ++mi) {
        float inv = 1.0f / rs[mi];
        int i = qt * 128 + w * 32 + mi * 16 + l16;
        short* aor = ao + (b * 1024 + i) * 1024 + h * 64;
        for (int dt = 0; dt < 4; ++dt) {
            bf16x4 o4;
            for (int r = 0; r < 4; ++r) o4[r] = f2bf(oaccT[mi][dt][r] * inv);
            *(bf16x4*)(aor + dt * 16 + quad * 4) = o4;   // 8B store, d contiguous
        }
    }
}

// ---------------- Out-proj GEMM: 3-stage pipeline + bias (R6) ----------------
__global__ __launch_bounds__(256) void gemm_proj(const short* __restrict__ A,
                                                 const short* __restrict__ Bt,
                                                 const float* __restrict__ bias,
                                                 float* __restrict__ out) {
    __shared__ alignas(16) short As[3][128][32];
    __shared__ alignas(16) short Bs[3][128][32];
    const int K = 1024;
    const int m0 = blockIdx.y * 128;
    const int n0 = blockIdx.x * 128;
    const int t = threadIdx.x;
    const int w = t >> 6, lane = t & 63, quad = lane >> 4, l16 = lane & 15;
    const int wm = (w >> 1) * 64, wn = (w & 1) * 64;
    const int srow = lane >> 2;
    const int sc8 = (lane & 3) * 8;

    const short* Abase = &A[(m0 + w * 32 + srow) * K + sc8];
    const short* Bbase = &Bt[(n0 + w * 32 + srow) * K + sc8];

    f32x4 acc[4][4];
    for (int mi = 0; mi < 4; ++mi)
        for (int ni = 0; ni < 4; ++ni)
            acc[mi][ni] = (f32x4){0.f, 0.f, 0.f, 0.f};

    #pragma unroll
    for (int p = 0; p < 2; ++p) {
        load_lds16(Abase + p * 32,          &As[p][w * 32][0]);
        load_lds16(Abase + 16 * K + p * 32, &As[p][w * 32 + 16][0]);
        load_lds16(Bbase + p * 32,          &Bs[p][w * 32][0]);
        load_lds16(Bbase + 16 * K + p * 32, &Bs[p][w * 32 + 16][0]);
    }

    #pragma unroll
    for (int it = 0; it < 32; ++it) {
        if (it == 31) asm volatile("s_waitcnt vmcnt(0) lgkmcnt(0)" ::: "memory");
        else          asm volatile("s_waitcnt vmcnt(4) lgkmcnt(0)" ::: "memory");
        asm volatile("s_barrier" ::: "memory");
        if (it < 30) {
            const int b2 = (it + 2) % 3;
            load_lds16(Abase + (it + 2) * 32,          &As[b2][w * 32][0]);
            load_lds16(Abase + 16 * K + (it + 2) * 32, &As[b2][w * 32 + 16][0]);
            load_lds16(Bbase + (it + 2) * 32,          &Bs[b2][w * 32][0]);
            load_lds16(Bbase + 16 * K + (it + 2) * 32, &Bs[b2][w * 32 + 16][0]);
        }
        const int cb = it % 3;
        bf16x8 af[4], bfr[4];
        for (int i = 0; i < 4; ++i) af[i]  = *(const bf16x8*)&As[cb][wm + i * 16 + l16][quad * 8];
        for (int i = 0; i < 4; ++i) bfr[i] = *(const bf16x8*)&Bs[cb][wn + i * 16 + l16][quad * 8];
        for (int mi = 0; mi < 4; ++mi)
            for (int ni = 0; ni < 4; ++ni)
                acc[mi][ni] = __builtin_amdgcn_mfma_f32_16x16x32_bf16(af[mi], bfr[ni], acc[mi][ni], 0, 0, 0);
    }

    for (int ni = 0; ni < 4; ++ni) {
        int col = n0 + wn + ni * 16 + l16;
        float bv = bias[col];
        for (int mi = 0; mi < 4; ++mi) {
            for (int r = 0; r < 4; ++r) {
                int m = m0 + wm + mi * 16 + quad * 4 + r;
                out[m * 1024 + col] = acc[mi][ni][r] + bv;
            }
        }
    }
}

extern "C" void kernel_launch(void* const* d_in, const int* in_sizes, int n_in,
                              void* d_out, int out_size, void* d_ws, size_t ws_size,
                              hipStream_t stream) {
    const float* x      = (const float*)d_in[0];
    const float* w_qkv  = (const float*)d_in[1];
    const float* w_proj = (const float*)d_in[2];
    const float* b_proj = (const float*)d_in[3];
    float* out = (float*)d_out;

    char* ws = (char*)d_ws;
    short* xb     = (short*)(ws);
    short* wqkvb  = (short*)(ws + 16777216);
    short* wprojb = (short*)(ws + 23068672);
    short* qb     = (short*)(ws + 25165824);
    short* kb     = (short*)(ws + 41943040);
    short* vtb    = (short*)(ws + 58720256);
    short* aob    = (short*)(ws + 75497472);

    convert_all<<<12288, 256, 0, stream>>>(x, w_qkv, w_proj, xb, wqkvb, wprojb);
    gemm_qkv<<<dim3(24, 64), 256, 0, stream>>>(xb, wqkvb, qb, kb, vtb);
    attn_kernel<<<dim3(8, 128), 256, 0, stream>>>(qb, kb, vtb, aob);
    gemm_proj<<<dim3(8, 64), 256, 0, stream>>>(aob, wprojb, b_proj, out);
}

// Round 9
// 265.569 us; speedup vs baseline: 1.1819x; 1.0053x over previous
//
#include <hip/hip_runtime.h>

// B=8, N=1024, C=1024, H=16, HD=64
// R9: GEMMs/convert unchanged from R8 (known-good 98us qkv).
//     Attention: double-buffered Ks/Vs -> ONE barrier per jt; fragment reads
//     interleaved with MFMAs (LDS pipe and matrix pipe overlap); staging
//     ds_writes after compute so global prefetch latency hides behind MFMAs.
//     Register-resident P via S^T operand swap (R8-verified layouts).

typedef __attribute__((ext_vector_type(8))) short bf16x8;
typedef __attribute__((ext_vector_type(4))) short bf16x4;
typedef __attribute__((ext_vector_type(4))) float f32x4;

__device__ __forceinline__ short f2bf(float f) {
    union { float f; unsigned u; } x;
    x.f = f;
    unsigned r = x.u + 0x7fffu + ((x.u >> 16) & 1u);  // RNE
    return (short)(r >> 16);
}

__device__ __forceinline__ void load_lds16(const void* g, void* l) {
    __builtin_amdgcn_global_load_lds((const __attribute__((address_space(1))) unsigned*)g,
                                     (__attribute__((address_space(3))) unsigned*)l,
                                     16, 0, 0);
}

// ---------------- merged fp32 -> bf16 convert ----------------
__global__ __launch_bounds__(256) void convert_all(const float* __restrict__ x,
                                                   const float* __restrict__ wqkv,
                                                   const float* __restrict__ wproj,
                                                   short* __restrict__ xb,
                                                   short* __restrict__ wqkvb,
                                                   short* __restrict__ wprojb) {
    int i = blockIdx.x * 256 + threadIdx.x;
    const float* src;
    short* dst;
    int j;
    if (i < 2097152)      { src = x;     dst = xb;     j = i; }
    else if (i < 2883584) { src = wqkv;  dst = wqkvb;  j = i - 2097152; }
    else                  { src = wproj; dst = wprojb; j = i - 2883584; }
    float4 v = *(const float4*)(src + j * 4);
    unsigned lo = (unsigned short)f2bf(v.x) | ((unsigned)(unsigned short)f2bf(v.y) << 16);
    unsigned hi = (unsigned short)f2bf(v.z) | ((unsigned)(unsigned short)f2bf(v.w) << 16);
    uint2 p; p.x = lo; p.y = hi;
    *(uint2*)(dst + j * 4) = p;
}

// ---------------- QKV GEMM: 3-stage pipeline, vmcnt(4) barriers (R6/R8) ----------------
__global__ __launch_bounds__(256) void gemm_qkv(const short* __restrict__ A,
                                                const short* __restrict__ Bt,
                                                short* __restrict__ q,
                                                short* __restrict__ k,
                                                short* __restrict__ vt) {
    __shared__ alignas(16) short As[3][128][32];
    __shared__ alignas(16) short Bs[3][128][32];
    const int K = 1024;
    const int m0 = blockIdx.y * 128;
    const int n0 = blockIdx.x * 128;
    const int t = threadIdx.x;
    const int w = t >> 6, lane = t & 63, quad = lane >> 4, l16 = lane & 15;
    const int wm = (w >> 1) * 64, wn = (w & 1) * 64;
    const int srow = lane >> 2;
    const int sc8 = (lane & 3) * 8;

    const short* Abase = &A[(m0 + w * 32 + srow) * K + sc8];
    const short* Bbase = &Bt[(n0 + w * 32 + srow) * K + sc8];

    f32x4 acc[4][4];
    for (int mi = 0; mi < 4; ++mi)
        for (int ni = 0; ni < 4; ++ni)
            acc[mi][ni] = (f32x4){0.f, 0.f, 0.f, 0.f};

    #pragma unroll
    for (int p = 0; p < 2; ++p) {
        load_lds16(Abase + p * 32,          &As[p][w * 32][0]);
        load_lds16(Abase + 16 * K + p * 32, &As[p][w * 32 + 16][0]);
        load_lds16(Bbase + p * 32,          &Bs[p][w * 32][0]);
        load_lds16(Bbase + 16 * K + p * 32, &Bs[p][w * 32 + 16][0]);
    }

    #pragma unroll
    for (int it = 0; it < 32; ++it) {
        if (it == 31) asm volatile("s_waitcnt vmcnt(0) lgkmcnt(0)" ::: "memory");
        else          asm volatile("s_waitcnt vmcnt(4) lgkmcnt(0)" ::: "memory");
        asm volatile("s_barrier" ::: "memory");
        if (it < 30) {
            const int b2 = (it + 2) % 3;
            load_lds16(Abase + (it + 2) * 32,          &As[b2][w * 32][0]);
            load_lds16(Abase + 16 * K + (it + 2) * 32, &As[b2][w * 32 + 16][0]);
            load_lds16(Bbase + (it + 2) * 32,          &Bs[b2][w * 32][0]);
            load_lds16(Bbase + 16 * K + (it + 2) * 32, &Bs[b2][w * 32 + 16][0]);
        }
        const int cb = it % 3;
        bf16x8 af[4], bfr[4];
        for (int i = 0; i < 4; ++i) af[i]  = *(const bf16x8*)&As[cb][wm + i * 16 + l16][quad * 8];
        for (int i = 0; i < 4; ++i) bfr[i] = *(const bf16x8*)&Bs[cb][wn + i * 16 + l16][quad * 8];
        for (int mi = 0; mi < 4; ++mi)
            for (int ni = 0; ni < 4; ++ni)
                acc[mi][ni] = __builtin_amdgcn_mfma_f32_16x16x32_bf16(af[mi], bfr[ni], acc[mi][ni], 0, 0, 0);
    }

    const float QS = 0.125f * 1.44269504088896f;
    for (int ni = 0; ni < 4; ++ni) {
        int col = n0 + wn + ni * 16 + l16;
        int sect = col >> 10;
        int c = col & 1023;
        int h = c >> 6, d = c & 63;
        for (int mi = 0; mi < 4; ++mi) {
            for (int r = 0; r < 4; ++r) {
                int m = m0 + wm + mi * 16 + quad * 4 + r;
                int b = m >> 10, i = m & 1023;
                float v = acc[mi][ni][r];
                if (sect == 0)      q[((b * 16 + h) * 1024 + i) * 64 + d] = f2bf(v * QS);
                else if (sect == 1) k[((b * 16 + h) * 1024 + i) * 64 + d] = f2bf(v);
                else                vt[((b * 16 + h) * 64 + d) * 1024 + i] = f2bf(v);
            }
        }
    }
}

// ---------------- Flash attention: dbuf K/V, 1 barrier/jt, register P ----------------
__global__ __launch_bounds__(256) void attn_kernel(const short* __restrict__ q,
                                                   const short* __restrict__ k,
                                                   const short* __restrict__ vt,
                                                   short* __restrict__ ao) {
    __shared__ alignas(16) short Ks[2][64][72];
    __shared__ alignas(16) short Vs[2][64][72];   // V^T tile [d][j]

    const int bh = blockIdx.y, qt = blockIdx.x;   // qt 0..7
    const int t = threadIdx.x, w = t >> 6, lane = t & 63, quad = lane >> 4, l16 = lane & 15;
    const short* qg = q  + (bh * 1024 + qt * 128) * 64;
    const short* kg = k  + bh * 65536;
    const short* vg = vt + bh * 65536;

    // Q fragments: Q[row=w*32+mi*16+l16][quad*8+j]
    bf16x8 qf[2][2];
    for (int mi = 0; mi < 2; ++mi) {
        const short* qr = qg + (w * 32 + mi * 16 + l16) * 64;
        qf[mi][0] = *(const bf16x8*)(qr + quad * 8);
        qf[mi][1] = *(const bf16x8*)(qr + 32 + quad * 8);
    }

    const int r0 = t >> 3,          c80 = (t & 7) * 8;
    const int r1 = (t + 256) >> 3,  c81 = c80;

    float rs[2] = {0.f, 0.f};
    f32x4 oaccT[2][4];   // O^T: [mi][dt], row d=dt*16+quad*4+r, col m=l16
    for (int mi = 0; mi < 2; ++mi)
        for (int dt = 0; dt < 4; ++dt) oaccT[mi][dt] = (f32x4){0.f, 0.f, 0.f, 0.f};

    // stage tile 0 -> buffer 0
    {
        float4 a = *(const float4*)&kg[r0 * 64 + c80];
        float4 b = *(const float4*)&kg[r1 * 64 + c81];
        float4 c = *(const float4*)&vg[r0 * 1024 + c80];
        float4 d = *(const float4*)&vg[r1 * 1024 + c81];
        *(float4*)&Ks[0][r0][c80] = a;  *(float4*)&Ks[0][r1][c81] = b;
        *(float4*)&Vs[0][r0][c80] = c;  *(float4*)&Vs[0][r1][c81] = d;
    }

    for (int jt = 0; jt < 16; ++jt) {
        const int cur = jt & 1;
        // single barrier: buf[cur] writes visible; buf[cur^1] reads (jt-1) retired
        asm volatile("s_waitcnt lgkmcnt(0)" ::: "memory");
        asm volatile("s_barrier" ::: "memory");

        // global prefetch of tile jt+1 (lands during the MFMA phase below)
        float4 kr0, kr1, vr0, vr1;
        if (jt < 15) {
            int jn = jt + 1;
            kr0 = *(const float4*)&kg[(jn * 64 + r0) * 64 + c80];
            kr1 = *(const float4*)&kg[(jn * 64 + r1) * 64 + c81];
            vr0 = *(const float4*)&vg[r0 * 1024 + jn * 64 + c80];
            vr1 = *(const float4*)&vg[r1 * 1024 + jn * 64 + c81];
        }

        // compute: fragment reads interleaved with MFMAs (LDS + matrix overlap)
        for (int js = 0; js < 4; ++js) {
            bf16x8 kf0 = *(const bf16x8*)&Ks[cur][js * 16 + l16][quad * 8];
            bf16x8 kf1 = *(const bf16x8*)&Ks[cur][js * 16 + l16][32 + quad * 8];
            bf16x4 vtf[4];
            for (int dt = 0; dt < 4; ++dt)
                vtf[dt] = *(const bf16x4*)&Vs[cur][dt * 16 + l16][js * 16 + quad * 4];
            for (int mi = 0; mi < 2; ++mi) {
                // S^T = K Q^T: lane holds S^T[js*16+quad*4+r][l16]
                f32x4 s = (f32x4){0.f, 0.f, 0.f, 0.f};
                s = __builtin_amdgcn_mfma_f32_16x16x32_bf16(kf0, qf[mi][0], s, 0, 0, 0);
                s = __builtin_amdgcn_mfma_f32_16x16x32_bf16(kf1, qf[mi][1], s, 0, 0, 0);
                bf16x4 pfrag;
                for (int r = 0; r < 4; ++r) {
                    float p = __builtin_amdgcn_exp2f(s[r]);
                    rs[mi] += p;
                    pfrag[r] = f2bf(p);
                }
                // O^T += V^T P^T (16x16x16, A=V^T frag, B=pfrag)
                for (int dt = 0; dt < 4; ++dt)
                    oaccT[mi][dt] = __builtin_amdgcn_mfma_f32_16x16x16bf16_1k(
                        vtf[dt], pfrag, oaccT[mi][dt], 0, 0, 0);
            }
        }

        // stage tile jt+1 into the other buffer (vmcnt wait inserted here)
        if (jt < 15) {
            const int nxt = cur ^ 1;
            *(float4*)&Ks[nxt][r0][c80] = kr0;  *(float4*)&Ks[nxt][r1][c81] = kr1;
            *(float4*)&Vs[nxt][r0][c80] = vr0;  *(float4*)&Vs[nxt][r1][c81] = vr1;
        }
    }

    // row-sum: add the 4 quad-partials for each m=l16
    for (int mi = 0; mi < 2; ++mi) {
        rs[mi] += __shfl_xor(rs[mi], 16, 64);
        rs[mi] += __shfl_xor(rs[mi], 32, 64);
    }

    const int b = bh >> 4, h = bh & 15;
    for (int mi = 0; mi < 2; ++mi) {
        float inv = 1.0f / rs[mi];
        int i = qt * 128 + w * 32 + mi * 16 + l16;
        short* aor = ao + (b * 1024 + i) * 1024 + h * 64;
        for (int dt = 0; dt < 4; ++dt) {
            bf16x4 o4;
            for (int r = 0; r < 4; ++r) o4[r] = f2bf(oaccT[mi][dt][r] * inv);
            *(bf16x4*)(aor + dt * 16 + quad * 4) = o4;   // 8B store, d contiguous
        }
    }
}

// ---------------- Out-proj GEMM: 3-stage pipeline + bias (R6/R8) ----------------
__global__ __launch_bounds__(256) void gemm_proj(const short* __restrict__ A,
                                                 const short* __restrict__ Bt,
                                                 const float* __restrict__ bias,
                                                 float* __restrict__ out) {
    __shared__ alignas(16) short As[3][128][32];
    __shared__ alignas(16) short Bs[3][128][32];
    const int K = 1024;
    const int m0 = blockIdx.y * 128;
    const int n0 = blockIdx.x * 128;
    const int t = threadIdx.x;
    const int w = t >> 6, lane = t & 63, quad = lane >> 4, l16 = lane & 15;
    const int wm = (w >> 1) * 64, wn = (w & 1) * 64;
    const int srow = lane >> 2;
    const int sc8 = (lane & 3) * 8;

    const short* Abase = &A[(m0 + w * 32 + srow) * K + sc8];
    const short* Bbase = &Bt[(n0 + w * 32 + srow) * K + sc8];

    f32x4 acc[4][4];
    for (int mi = 0; mi < 4; ++mi)
        for (int ni = 0; ni < 4; ++ni)
            acc[mi][ni] = (f32x4){0.f, 0.f, 0.f, 0.f};

    #pragma unroll
    for (int p = 0; p < 2; ++p) {
        load_lds16(Abase + p * 32,          &As[p][w * 32][0]);
        load_lds16(Abase + 16 * K + p * 32, &As[p][w * 32 + 16][0]);
        load_lds16(Bbase + p * 32,          &Bs[p][w * 32][0]);
        load_lds16(Bbase + 16 * K + p * 32, &Bs[p][w * 32 + 16][0]);
    }

    #pragma unroll
    for (int it = 0; it < 32; ++it) {
        if (it == 31) asm volatile("s_waitcnt vmcnt(0) lgkmcnt(0)" ::: "memory");
        else          asm volatile("s_waitcnt vmcnt(4) lgkmcnt(0)" ::: "memory");
        asm volatile("s_barrier" ::: "memory");
        if (it < 30) {
            const int b2 = (it + 2) % 3;
            load_lds16(Abase + (it + 2) * 32,          &As[b2][w * 32][0]);
            load_lds16(Abase + 16 * K + (it + 2) * 32, &As[b2][w * 32 + 16][0]);
            load_lds16(Bbase + (it + 2) * 32,          &Bs[b2][w * 32][0]);
            load_lds16(Bbase + 16 * K + (it + 2) * 32, &Bs[b2][w * 32 + 16][0]);
        }
        const int cb = it % 3;
        bf16x8 af[4], bfr[4];
        for (int i = 0; i < 4; ++i) af[i]  = *(const bf16x8*)&As[cb][wm + i * 16 + l16][quad * 8];
        for (int i = 0; i < 4; ++i) bfr[i] = *(const bf16x8*)&Bs[cb][wn + i * 16 + l16][quad * 8];
        for (int mi = 0; mi < 4; ++mi)
            for (int ni = 0; ni < 4; ++ni)
                acc[mi][ni] = __builtin_amdgcn_mfma_f32_16x16x32_bf16(af[mi], bfr[ni], acc[mi][ni], 0, 0, 0);
    }

    for (int ni = 0; ni < 4; ++ni) {
        int col = n0 + wn + ni * 16 + l16;
        float bv = bias[col];
        for (int mi = 0; mi < 4; ++mi) {
            for (int r = 0; r < 4; ++r) {
                int m = m0 + wm + mi * 16 + quad * 4 + r;
                out[m * 1024 + col] = acc[mi][ni][r] + bv;
            }
        }
    }
}

extern "C" void kernel_launch(void* const* d_in, const int* in_sizes, int n_in,
                              void* d_out, int out_size, void* d_ws, size_t ws_size,
                              hipStream_t stream) {
    const float* x      = (const float*)d_in[0];
    const float* w_qkv  = (const float*)d_in[1];
    const float* w_proj = (const float*)d_in[2];
    const float* b_proj = (const float*)d_in[3];
    float* out = (float*)d_out;

    char* ws = (char*)d_ws;
    short* xb     = (short*)(ws);
    short* wqkvb  = (short*)(ws + 16777216);
    short* wprojb = (short*)(ws + 23068672);
    short* qb     = (short*)(ws + 25165824);
    short* kb     = (short*)(ws + 41943040);
    short* vtb    = (short*)(ws + 58720256);
    short* aob    = (short*)(ws + 75497472);

    convert_all<<<12288, 256, 0, stream>>>(x, w_qkv, w_proj, xb, wqkvb, wprojb);
    gemm_qkv<<<dim3(24, 64), 256, 0, stream>>>(xb, wqkvb, qb, kb, vtb);
    attn_kernel<<<dim3(8, 128), 256, 0, stream>>>(qb, kb, vtb, aob);
    gemm_proj<<<dim3(8, 64), 256, 0, stream>>>(aob, wprojb, b_proj, out);
}